// Round 3
// baseline (716.242 us; speedup 1.0000x reference)
//
#include <hip/hip_runtime.h>

// Convolution_1228360646680 — equivariant graph conv, fused CSR-gather version
// N=25000, E=400000, MUL=32, NSC=8, HID=64
//
// Pipeline:
//   prep:      stage scaled Wfc1 (8x64) and transposed+scaled Wfc2^T (128x64)
//   node_in:   xsv1[n][128] = a[n]/sqrt(32) * (x @ w1)   {xs1 | xv1 interleaved}
//   CSR build: count -> scan -> scatter  (edge ids grouped by dst)
//   gather_fused: block per node; per 4-edge chunk wave w computes h(edge)
//                 into LDS, then all 256 threads dot vs register-resident
//                 W2T column and accumulate their mid feature. No wbuf.
//   node_out:  out[n][128] = b[n]/sqrt(64)/sqrt(16) * (mid @ w2)
// Fallback to atomic scatter-add if ws_size too small.

__global__ __launch_bounds__(256) void prep_kernel(
    const float* __restrict__ Wfc1, const float* __restrict__ Wfc2,
    float* __restrict__ W1s, float* __restrict__ W2T)
{
    int t = blockIdx.x * 256 + threadIdx.x;
    const float inv_sqrt_nsc = 0.35355339059327373f; // 1/sqrt(8)
    if (t < 8 * 64) W1s[t] = Wfc1[t] * inv_sqrt_nsc;
    if (t < 64 * 128) {
        int r = t >> 7, c = t & 127;
        W2T[c * 64 + r] = Wfc2[t] * 0.125f;          // 1/sqrt(64)
    }
}

__global__ __launch_bounds__(256) void node_in_kernel(
    const float* __restrict__ node_input, const float* __restrict__ attr_in,
    const float* __restrict__ w1s, const float* __restrict__ w1v,
    float* __restrict__ xsv1, int n_nodes)
{
    __shared__ float sWs[1024], sWv[1024], srow[2][128];
    for (int k = threadIdx.x; k < 1024; k += 256) { sWs[k] = w1s[k]; sWv[k] = w1v[k]; }
    int j = threadIdx.x & 127;
    int half = threadIdx.x >> 7;
    int w = 0, i = 0;
    if (j >= 32) { int jj = j - 32; w = jj / 3; i = jj - 3 * w; }
    const float inv1 = 0.17677669529663687f; // 1/sqrt(32)
    for (int base = blockIdx.x * 2; base < n_nodes; base += gridDim.x * 2) {
        int n = base + half;
        __syncthreads();
        if (n < n_nodes) srow[half][j] = node_input[(size_t)n * 128 + j];
        __syncthreads();
        if (n < n_nodes) {
            float acc = 0.0f;
            if (j < 32) {
                #pragma unroll
                for (int u = 0; u < 32; u++) acc += srow[half][u] * sWs[u * 32 + j];
            } else {
                #pragma unroll
                for (int u = 0; u < 32; u++) acc += srow[half][32 + 3 * u + i] * sWv[u * 32 + w];
            }
            xsv1[(size_t)n * 128 + j] = acc * (attr_in[n] * inv1);
        }
    }
}

// ---------------- CSR build ----------------
__global__ __launch_bounds__(256) void count_kernel(
    const int* __restrict__ edst, int* __restrict__ counts, int n_edges)
{
    int e = blockIdx.x * 256 + threadIdx.x;
    if (e < n_edges) atomicAdd(&counts[edst[e]], 1);
}

__global__ __launch_bounds__(1024) void scan_kernel(
    const int* __restrict__ counts, int* __restrict__ offs, int* __restrict__ cursor, int n)
{
    __shared__ int part[1024];
    int tid = threadIdx.x;
    int chunk = (n + 1023) / 1024;
    int begin = tid * chunk;
    int end = begin + chunk; if (end > n) end = n;
    int s = 0;
    for (int i = begin; i < end; i++) s += counts[i];
    part[tid] = s;
    __syncthreads();
    for (int off = 1; off < 1024; off <<= 1) {
        int v = (tid >= off) ? part[tid - off] : 0;
        __syncthreads();
        part[tid] += v;
        __syncthreads();
    }
    int base = (tid == 0) ? 0 : part[tid - 1];
    for (int i = begin; i < end; i++) {
        offs[i] = base; cursor[i] = base;
        base += counts[i];
    }
    if (tid == 1023) offs[n] = part[1023];
}

__global__ __launch_bounds__(256) void scatter_kernel(
    const int* __restrict__ edst, int* __restrict__ cursor, int* __restrict__ elist, int n_edges)
{
    int e = blockIdx.x * 256 + threadIdx.x;
    if (e < n_edges) {
        int p = atomicAdd(&cursor[edst[e]], 1);
        elist[p] = e;
    }
}

// ---------------- fused gather: MLP + tensor product + segment sum ----------------
__global__ __launch_bounds__(256) void gather_fused_kernel(
    const float* __restrict__ escal,
    const float* __restrict__ W1s_g, const float* __restrict__ W2T_g,
    const float* __restrict__ xsv1, const int* __restrict__ esrc,
    const float* __restrict__ eattr,
    const int* __restrict__ offs, const int* __restrict__ elist,
    float* __restrict__ mid, int n_nodes)
{
    __shared__ alignas(16) float hbuf[2][4][64];
    int n = blockIdx.x;
    int tid = threadIdx.x;
    int wv = tid >> 6, lane = tid & 63;

    // per-lane first-layer weight column (for h-phase): W1s[k*64+lane]
    float w1c[8];
    #pragma unroll
    for (int k = 0; k < 8; k++) w1c[k] = W1s_g[k * 64 + lane];

    // feature-role decode (same mapping as validated round-1 gather)
    int kind, u = 0, i = 0, col;
    if (tid < 32)       { kind = 0; u = tid;       col = tid; }
    else if (tid < 64)  { kind = 1; u = tid - 32;  col = 96 + u; }
    else if (tid < 160) { int q = tid - 64;  u = q / 3; i = q - 3 * u; kind = 2; col = 32 + u; }
    else                { int q = tid - 160; u = q / 3; i = q - 3 * u; kind = 3; col = 64 + u; }

    // register-resident second-layer column: W2T[col][0..63]
    float w2c[64];
    #pragma unroll
    for (int k = 0; k < 16; k++) {
        float4 v = *reinterpret_cast<const float4*>(W2T_g + (size_t)col * 64 + 4 * k);
        w2c[4 * k]     = v.x; w2c[4 * k + 1] = v.y;
        w2c[4 * k + 2] = v.z; w2c[4 * k + 3] = v.w;
    }

    const float inv_sqrt3 = 0.5773502691896258f;
    int start = offs[n];
    int deg = offs[n + 1] - start;
    int nchunk = (deg + 3) >> 2;
    float acc = 0.0f;

    for (int ck = 0; ck < nchunk; ck++) {
        int base = start + ck * 4;
        int rem = deg - ck * 4;
        // h-phase: wave wv computes h for edge base+wv
        if (wv < rem) {
            int e = elist[base + wv];
            const float4 qa = *reinterpret_cast<const float4*>(escal + (size_t)e * 8);
            const float4 qb = *reinterpret_cast<const float4*>(escal + (size_t)e * 8 + 4);
            float a = qa.x * w1c[0] + qa.y * w1c[1] + qa.z * w1c[2] + qa.w * w1c[3]
                    + qb.x * w1c[4] + qb.y * w1c[5] + qb.z * w1c[6] + qb.w * w1c[7];
            hbuf[ck & 1][wv][lane] = a / (1.0f + __expf(-a));   // silu
        }
        __syncthreads();
        int cmax = rem < 4 ? rem : 4;
        for (int c = 0; c < cmax; c++) {
            int e = elist[base + c];
            int src = esrc[e];
            const float4 ea = *reinterpret_cast<const float4*>(eattr + (size_t)e * 4);
            const float* __restrict__ hb = hbuf[ck & 1][c];
            float wvl = 0.0f;
            #pragma unroll
            for (int t = 0; t < 64; t += 4) {
                float4 h4 = *reinterpret_cast<const float4*>(hb + t);
                wvl += h4.x * w2c[t] + h4.y * w2c[t + 1] + h4.z * w2c[t + 2] + h4.w * w2c[t + 3];
            }
            const float* __restrict__ nb = xsv1 + (size_t)src * 128;
            if (kind == 0) {
                acc += wvl * nb[u] * ea.x;
            } else if (kind == 1) {
                acc += wvl * (nb[32 + 3 * u] * ea.y + nb[33 + 3 * u] * ea.z + nb[34 + 3 * u] * ea.w) * inv_sqrt3;
            } else if (kind == 2) {
                float yvi = (i == 0) ? ea.y : (i == 1) ? ea.z : ea.w;
                acc += wvl * nb[u] * yvi;
            } else {
                acc += wvl * ea.x * nb[32 + 3 * u + i];
            }
        }
    }
    mid[(size_t)n * 256 + tid] = acc;
}

// ---------------- fallback atomic edge kernel (ws too small) ----------------
__global__ __launch_bounds__(256) void edge_kernel_atomic(
    const float* __restrict__ xsv1, const int* __restrict__ esrc, const int* __restrict__ edst,
    const float* __restrict__ eattr, const float* __restrict__ escal,
    const float* __restrict__ W1s, const float* __restrict__ W2T,
    float* __restrict__ mid, int n_edges)
{
    int e = blockIdx.x * 256 + threadIdx.x;
    if (e >= n_edges) return;
    const float4 qa = *reinterpret_cast<const float4*>(escal + (size_t)e * 8);
    const float4 qb = *reinterpret_cast<const float4*>(escal + (size_t)e * 8 + 4);
    float h[64];
    #pragma unroll
    for (int t = 0; t < 64; t++) {
        float acc = qa.x * W1s[t]       + qa.y * W1s[64 + t]
                  + qa.z * W1s[128 + t] + qa.w * W1s[192 + t]
                  + qb.x * W1s[256 + t] + qb.y * W1s[320 + t]
                  + qb.z * W1s[384 + t] + qb.w * W1s[448 + t];
        h[t] = acc / (1.0f + __expf(-acc));
    }
    int src = esrc[e], dst = edst[e];
    const float4 ea = *reinterpret_cast<const float4*>(eattr + (size_t)e * 4);
    const float ys = ea.x, yv0 = ea.y, yv1 = ea.z, yv2 = ea.w;
    const float* __restrict__ nb = xsv1 + (size_t)src * 128;
    float* __restrict__ op = mid + (size_t)dst * 256;
    const float inv_sqrt3 = 0.5773502691896258f;
    for (int u = 0; u < 32; u++) {
        float w0 = 0.f, w1 = 0.f, w2 = 0.f, w3 = 0.f;
        const float* __restrict__ r0 = W2T + (size_t)u * 64;
        const float* __restrict__ r1 = W2T + (size_t)(32 + u) * 64;
        const float* __restrict__ r2 = W2T + (size_t)(64 + u) * 64;
        const float* __restrict__ r3 = W2T + (size_t)(96 + u) * 64;
        #pragma unroll
        for (int t = 0; t < 64; t++) {
            float hv = h[t];
            w0 += hv * r0[t]; w1 += hv * r1[t]; w2 += hv * r2[t]; w3 += hv * r3[t];
        }
        float es  = nb[u];
        float ev0 = nb[32 + 3 * u], ev1 = nb[33 + 3 * u], ev2 = nb[34 + 3 * u];
        atomicAdd(op + u,      w0 * es * ys);
        atomicAdd(op + 32 + u, w3 * (ev0 * yv0 + ev1 * yv1 + ev2 * yv2) * inv_sqrt3);
        float a1 = w1 * es;
        atomicAdd(op + 64 + 3 * u, a1 * yv0);
        atomicAdd(op + 65 + 3 * u, a1 * yv1);
        atomicAdd(op + 66 + 3 * u, a1 * yv2);
        float a2 = w2 * ys;
        atomicAdd(op + 160 + 3 * u, a2 * ev0);
        atomicAdd(op + 161 + 3 * u, a2 * ev1);
        atomicAdd(op + 162 + 3 * u, a2 * ev2);
    }
}

__global__ __launch_bounds__(256) void node_out_kernel(
    const float* __restrict__ mid, const float* __restrict__ attr_out,
    const float* __restrict__ w2s, const float* __restrict__ w2v,
    float* __restrict__ out, int n_nodes)
{
    __shared__ float sS0[1024], sS1[1024], sV0[1024], sV1[1024];
    for (int k = threadIdx.x; k < 1024; k += 256) {
        sS0[k] = w2s[k]; sS1[k] = w2s[1024 + k];
        sV0[k] = w2v[k]; sV1[k] = w2v[1024 + k];
    }
    __syncthreads();
    int j = threadIdx.x & 127;
    int half = threadIdx.x >> 7;
    int w = 0, i = 0;
    if (j >= 32) { int jj = j - 32; w = jj / 3; i = jj - 3 * w; }
    const float scale = 0.125f * 0.25f; // 1/sqrt(64) * 1/sqrt(16)
    for (int base = blockIdx.x * 2; base < n_nodes; base += gridDim.x * 2) {
        int n = base + half;
        if (n >= n_nodes) continue;
        const float* __restrict__ mr = mid + (size_t)n * 256;
        float acc = 0.0f;
        if (j < 32) {
            #pragma unroll
            for (int u = 0; u < 32; u++)
                acc += mr[u] * sS0[u * 32 + j] + mr[32 + u] * sS1[u * 32 + j];
        } else {
            #pragma unroll
            for (int u = 0; u < 32; u++)
                acc += mr[64 + 3 * u + i] * sV0[u * 32 + w] + mr[160 + 3 * u + i] * sV1[u * 32 + w];
        }
        out[(size_t)n * 128 + j] = acc * (attr_out[n] * scale);
    }
}

extern "C" void kernel_launch(void* const* d_in, const int* in_sizes, int n_in,
                              void* d_out, int out_size, void* d_ws, size_t ws_size,
                              hipStream_t stream)
{
    const float* node_input = (const float*)d_in[0];
    const float* attr_in    = (const float*)d_in[1];
    const float* attr_out   = (const float*)d_in[2];
    const int*   esrc       = (const int*)d_in[3];
    const int*   edst       = (const int*)d_in[4];
    const float* eattr      = (const float*)d_in[5];
    const float* escal      = (const float*)d_in[6];
    const float* w1s        = (const float*)d_in[7];
    const float* w1v        = (const float*)d_in[8];
    const float* Wfc1       = (const float*)d_in[9];
    const float* Wfc2       = (const float*)d_in[10];
    const float* w2s        = (const float*)d_in[11];
    const float* w2v        = (const float*)d_in[12];
    float* out = (float*)d_out;

    int n_nodes = in_sizes[0] / 128;
    int n_edges = in_sizes[3];

    // workspace layout
    float* ws   = (float*)d_ws;
    float* xsv1 = ws;                                    // n_nodes*128
    float* W1s  = xsv1 + (size_t)n_nodes * 128;          // 512
    float* W2T  = W1s + 512;                             // 8192
    float* mid  = W2T + 8192;                            // n_nodes*256
    int*   counts = (int*)(mid + (size_t)n_nodes * 256); // n_nodes
    int*   offs   = counts + n_nodes;                    // n_nodes+1
    int*   cursor = offs + n_nodes + 1;                  // n_nodes
    int*   elist  = cursor + n_nodes;                    // n_edges

    size_t needed = (size_t)((char*)(elist + n_edges) - (char*)d_ws);

    prep_kernel<<<32, 256, 0, stream>>>(Wfc1, Wfc2, W1s, W2T);
    node_in_kernel<<<2048, 256, 0, stream>>>(node_input, attr_in, w1s, w1v, xsv1, n_nodes);

    if (ws_size >= needed) {
        // CSR-gather path: no scattered fp32 atomics, no materialized wbuf
        hipMemsetAsync(counts, 0, (size_t)n_nodes * sizeof(int), stream);
        count_kernel<<<(n_edges + 255) / 256, 256, 0, stream>>>(edst, counts, n_edges);
        scan_kernel<<<1, 1024, 0, stream>>>(counts, offs, cursor, n_nodes);
        scatter_kernel<<<(n_edges + 255) / 256, 256, 0, stream>>>(edst, cursor, elist, n_edges);
        gather_fused_kernel<<<n_nodes, 256, 0, stream>>>(escal, W1s, W2T, xsv1, esrc, eattr,
                                                         offs, elist, mid, n_nodes);
    } else {
        hipMemsetAsync(mid, 0, (size_t)n_nodes * 256 * sizeof(float), stream);
        edge_kernel_atomic<<<(n_edges + 255) / 256, 256, 0, stream>>>(
            xsv1, esrc, edst, eattr, escal, W1s, W2T, mid, n_edges);
    }
    node_out_kernel<<<2048, 256, 0, stream>>>(mid, attr_out, w2s, w2v, out, n_nodes);
}